// Round 14
// baseline (185.770 us; speedup 1.0000x reference)
//
#include <hip/hip_runtime.h>
#include <math.h>

#define P 16384               // 128*128 pixels
#define SCALEF 0.08838834764831845f             // 128^-0.5
#define QSCALE 0.12752075616290145f             // SCALEF * log2(e)

typedef short bf16x8 __attribute__((ext_vector_type(8)));
typedef float f32x4 __attribute__((ext_vector_type(4)));

__device__ __forceinline__ unsigned short f2bf(float x) {
  union { float f; unsigned int u; } v; v.f = x;
  unsigned int r = v.u + 0x7fffu + ((v.u >> 16) & 1u);  // RNE
  return (unsigned short)(r >> 16);
}
__device__ __forceinline__ unsigned int packbf(float a, float b) {
  return (unsigned int)f2bf(a) | ((unsigned int)f2bf(b) << 16);
}
// pack two f32 -> bf16 pair (round-half-up) via v_perm: 3 VALU
__device__ __forceinline__ unsigned int pr2(float a, float b) {
  union { float f; unsigned int u; } ua, ub; ua.f = a; ub.f = b;
  return __builtin_amdgcn_perm(ub.u + 0x8000u, ua.u + 0x8000u, 0x07060302u);
}
// pack two f32 -> bf16 pair in ONE VALU (RNE)
__device__ __forceinline__ unsigned int pk2(float a, float b) {
  unsigned int r;
  asm("v_cvt_pk_bf16_f32 %0, %1, %2" : "=v"(r) : "v"(a), "v"(b));
  return r;
}
#define EXP2F(x) __builtin_amdgcn_exp2f(x)

// ---------------------------------------------------------------------------
// Split-bf16 MFMA GEMM for 1x1 conv: out[oc][p] = sum_ic w[oc][ic]*in[ic][p].
// NS=2: x=H+L, 3 terms (err ~1e-5 rel). Block: 64 oc x JT*64 px, 4 waves.
// ---------------------------------------------------------------------------
template<int NS, int JT>
__global__ __launch_bounds__(256) void k_conv_mfma(
    const float* __restrict__ in, const float* __restrict__ w,
    const float* __restrict__ bias, float* __restrict__ out,
    const int IC, const int in_zstr, const int out_zstr)
{
  const int p0  = blockIdx.x * (JT * 64);
  const int oc0 = blockIdx.y * 64;
  in  += (size_t)blockIdx.z * (size_t)in_zstr;
  out += (size_t)blockIdx.z * (size_t)out_zstr;
  const int tid = threadIdx.x;
  const int wv = tid >> 6;
  const int lane = tid & 63;
  const int qi = lane & 15, g = lane >> 4;

  __shared__ __align__(16) unsigned int bS[NS][JT * 64 * 16];
  __shared__ __align__(16) unsigned int aS[NS][64 * 16];

  const f32x4 fz = {0.f, 0.f, 0.f, 0.f};
  f32x4 acc[JT][4];
  #pragma unroll
  for (int j = 0; j < JT; ++j)
    #pragma unroll
    for (int o = 0; o < 4; ++o) acc[j][o] = fz;

  for (int k0 = 0; k0 < IC; k0 += 32) {
    __syncthreads();
    // ---- stage B: thread = k-pair (tid>>4), JT*4 px starting (tid&15)*JT*4
    {
      const int kB = tid >> 4;
      const int pB = (tid & 15) * (JT * 4);
      const float* r0 = in + (size_t)(k0 + 2 * kB) * P + p0 + pB;
      #pragma unroll
      for (int half = 0; half < JT / 2; ++half) {
        float x0[8], x1[8];
        #pragma unroll
        for (int v = 0; v < 2; ++v) {
          float4 a = ((const float4*)r0)[half * 2 + v];
          float4 c = ((const float4*)(r0 + P))[half * 2 + v];
          x0[4*v] = a.x; x0[4*v+1] = a.y; x0[4*v+2] = a.z; x0[4*v+3] = a.w;
          x1[4*v] = c.x; x1[4*v+1] = c.y; x1[4*v+2] = c.z; x1[4*v+3] = c.w;
        }
        #pragma unroll
        for (int ii = 0; ii < 8; ++ii) {
          const int i8 = (ii + tid) & 7;           // bank rotation
          const int i = half * 8 + i8;
          const unsigned idx = (unsigned)((pB + i) * 16 + (kB ^ ((i & 3) << 2)));
          const unsigned u0 = __float_as_uint(x0[i8]);
          const unsigned u1 = __float_as_uint(x1[i8]);
          bS[0][idx] = __builtin_amdgcn_perm(u1, u0, 0x07060302u);
          const float r0f = x0[i8] - __uint_as_float(u0 & 0xffff0000u);
          const float r1f = x1[i8] - __uint_as_float(u1 & 0xffff0000u);
          bS[1][idx] = pr2(r0f, r1f);
        }
      }
    }
    // ---- stage A: thread = oc row tid>>2, k span (tid&3)*8 ----
    {
      const int oA = tid >> 2;
      const int kA = (tid & 3) * 8;
      const float* rw = w + (size_t)(oc0 + oA) * IC + k0 + kA;
      float4 wa = ((const float4*)rw)[0];
      float4 wb = ((const float4*)rw)[1];
      float y[8] = {wa.x, wa.y, wa.z, wa.w, wb.x, wb.y, wb.z, wb.w};
      #pragma unroll
      for (int i = 0; i < 4; ++i) {
        const int dd = (kA >> 1) + i;
        const unsigned idx = (unsigned)(oA * 16 + (dd ^ ((oA & 3) << 2)));
        const unsigned u0 = __float_as_uint(y[2*i]);
        const unsigned u1 = __float_as_uint(y[2*i+1]);
        aS[0][idx] = __builtin_amdgcn_perm(u1, u0, 0x07060302u);
        const float r0f = y[2*i]   - __uint_as_float(u0 & 0xffff0000u);
        const float r1f = y[2*i+1] - __uint_as_float(u1 & 0xffff0000u);
        aS[1][idx] = pr2(r0f, r1f);
      }
    }
    __syncthreads();

    bf16x8 aF[4][NS];
    #pragma unroll
    for (int o = 0; o < 4; ++o) {
      const unsigned ab = (unsigned)((o * 16 + qi) * 16 + 4 * (g ^ (qi & 3)));
      #pragma unroll
      for (int s = 0; s < NS; ++s)
        aF[o][s] = *(const bf16x8*)&aS[s][ab];
    }
    #pragma unroll
    for (int j = 0; j < JT; ++j) {
      const unsigned bb = (unsigned)(((wv * JT + j) * 16 + qi) * 16 + 4 * (g ^ (qi & 3)));
      const bf16x8 b0 = *(const bf16x8*)&bS[0][bb];
      const bf16x8 b1 = *(const bf16x8*)&bS[1][bb];
      #pragma unroll
      for (int o = 0; o < 4; ++o) {
        acc[j][o] = __builtin_amdgcn_mfma_f32_16x16x32_bf16(aF[o][0], b0, acc[j][o], 0, 0, 0);
        acc[j][o] = __builtin_amdgcn_mfma_f32_16x16x32_bf16(aF[o][0], b1, acc[j][o], 0, 0, 0);
        acc[j][o] = __builtin_amdgcn_mfma_f32_16x16x32_bf16(aF[o][1], b0, acc[j][o], 0, 0, 0);
      }
    }
  }

  float bv[4][4];
  #pragma unroll
  for (int o = 0; o < 4; ++o)
    #pragma unroll
    for (int t = 0; t < 4; ++t)
      bv[o][t] = bias ? bias[oc0 + o * 16 + 4 * g + t] : 0.f;

  #pragma unroll
  for (int j = 0; j < JT; ++j) {
    const int px = p0 + (wv * JT + j) * 16 + qi;
    #pragma unroll
    for (int o = 0; o < 4; ++o)
      #pragma unroll
      for (int t = 0; t < 4; ++t)
        out[(size_t)(oc0 + o * 16 + 4 * g + t) * P + px] = acc[j][o][t] + bv[o][t];
  }
}

// ---------------------------------------------------------------------------
// Fused mlp+proj GEMM (IC=384) + LayerNorm epilogue -> writes d_out directly.
// ---------------------------------------------------------------------------
__global__ __launch_bounds__(256) void k_projln(
    const float* __restrict__ in, const float* __restrict__ w,
    const float* __restrict__ bias, const float* __restrict__ ln_g,
    const float* __restrict__ ln_b, float* __restrict__ out)
{
  const int p0 = blockIdx.x * 64;
  const int tid = threadIdx.x;
  const int wv = tid >> 6;
  const int lane = tid & 63;
  const int qi = lane & 15, g = lane >> 4;

  __shared__ __align__(16) unsigned int bS[2][64 * 16];
  __shared__ __align__(16) unsigned int aS[2][128 * 16];

  const f32x4 fz = {0.f, 0.f, 0.f, 0.f};
  f32x4 acc[8];
  #pragma unroll
  for (int o = 0; o < 8; ++o) acc[o] = fz;

  for (int k0 = 0; k0 < 384; k0 += 32) {
    __syncthreads();
    // stage B: thread = k-pair (tid>>4), 4 px at (tid&15)*4
    {
      const int kB = tid >> 4;
      const int pB = (tid & 15) * 4;
      const float* r0 = in + (size_t)(k0 + 2 * kB) * P + p0 + pB;
      float4 a = *(const float4*)r0;
      float4 c = *(const float4*)(r0 + P);
      const float x0[4] = {a.x, a.y, a.z, a.w};
      const float x1[4] = {c.x, c.y, c.z, c.w};
      #pragma unroll
      for (int i = 0; i < 4; ++i) {
        const unsigned idx = (unsigned)((pB + i) * 16 + (kB ^ (i << 2)));
        const unsigned u0 = __float_as_uint(x0[i]);
        const unsigned u1 = __float_as_uint(x1[i]);
        bS[0][idx] = __builtin_amdgcn_perm(u1, u0, 0x07060302u);
        const float r0f = x0[i] - __uint_as_float(u0 & 0xffff0000u);
        const float r1f = x1[i] - __uint_as_float(u1 & 0xffff0000u);
        bS[1][idx] = pr2(r0f, r1f);
      }
    }
    // stage A: thread = oc row (tid>>1), k span (tid&1)*16
    {
      const int oA = tid >> 1;
      const int kA = (tid & 1) * 16;
      const float* rw = w + (size_t)oA * 384 + k0 + kA;
      float4 wa = ((const float4*)rw)[0];
      float4 wb = ((const float4*)rw)[1];
      float4 wc = ((const float4*)rw)[2];
      float4 wd = ((const float4*)rw)[3];
      const float y[16] = {wa.x, wa.y, wa.z, wa.w, wb.x, wb.y, wb.z, wb.w,
                           wc.x, wc.y, wc.z, wc.w, wd.x, wd.y, wd.z, wd.w};
      #pragma unroll
      for (int i = 0; i < 8; ++i) {
        const int dd = (kA >> 1) + i;
        const unsigned idx = (unsigned)(oA * 16 + (dd ^ ((oA & 3) << 2)));
        const unsigned u0 = __float_as_uint(y[2*i]);
        const unsigned u1 = __float_as_uint(y[2*i+1]);
        aS[0][idx] = __builtin_amdgcn_perm(u1, u0, 0x07060302u);
        const float r0f = y[2*i]   - __uint_as_float(u0 & 0xffff0000u);
        const float r1f = y[2*i+1] - __uint_as_float(u1 & 0xffff0000u);
        aS[1][idx] = pr2(r0f, r1f);
      }
    }
    __syncthreads();

    const unsigned bb = (unsigned)((wv * 16 + qi) * 16 + 4 * (g ^ (qi & 3)));
    const bf16x8 b0 = *(const bf16x8*)&bS[0][bb];
    const bf16x8 b1 = *(const bf16x8*)&bS[1][bb];
    #pragma unroll
    for (int o = 0; o < 8; ++o) {
      const unsigned ab = (unsigned)((o * 16 + qi) * 16 + 4 * (g ^ (qi & 3)));
      const bf16x8 a0 = *(const bf16x8*)&aS[0][ab];
      const bf16x8 a1 = *(const bf16x8*)&aS[1][ab];
      acc[o] = __builtin_amdgcn_mfma_f32_16x16x32_bf16(a0, b0, acc[o], 0, 0, 0);
      acc[o] = __builtin_amdgcn_mfma_f32_16x16x32_bf16(a0, b1, acc[o], 0, 0, 0);
      acc[o] = __builtin_amdgcn_mfma_f32_16x16x32_bf16(a1, b0, acc[o], 0, 0, 0);
    }
  }

  // epilogue: bias + LayerNorm over the 128 channels of pixel px
  const int px = p0 + wv * 16 + qi;
  float vch[8][4];
  float sum = 0.f, sq = 0.f;
  #pragma unroll
  for (int o = 0; o < 8; ++o)
    #pragma unroll
    for (int t = 0; t < 4; ++t) {
      const float v = acc[o][t] + bias[o * 16 + 4 * g + t];
      vch[o][t] = v; sum += v; sq += v * v;
    }
  sum += __shfl_xor(sum, 16, 64); sum += __shfl_xor(sum, 32, 64);
  sq  += __shfl_xor(sq, 16, 64);  sq  += __shfl_xor(sq, 32, 64);
  const float mu = sum * (1.f / 128.f);
  const float var = sq * (1.f / 128.f) - mu * mu;
  const float rs = rsqrtf(var + 1e-5f);
  #pragma unroll
  for (int o = 0; o < 8; ++o)
    #pragma unroll
    for (int t = 0; t < 4; ++t) {
      const int oc = o * 16 + 4 * g + t;
      out[(size_t)oc * P + px] = (vch[o][t] - mu) * rs * ln_g[oc] + ln_b[oc];
    }
}

// ---------------------------------------------------------------------------
// Fold mlp into proj (Wc = proj_w x blockdiag(mlp_w), bc = proj_w x mlp_b).
// ---------------------------------------------------------------------------
__global__ __launch_bounds__(128) void k_fold(
    const float* __restrict__ proj_w, const float* __restrict__ mlp_w,
    const float* __restrict__ mlp_b, float* __restrict__ Wc,
    float* __restrict__ bc)
{
  const int o = blockIdx.x;      // 0..127
  const int b = blockIdx.y;      // 0..2
  const int i = threadIdx.x;     // 0..127
  const float* pw = proj_w + o * 384 + b * 128;
  float acc = 0.f;
  for (int j = 0; j < 128; ++j)
    acc += pw[j] * mlp_w[j * 128 + i];
  Wc[o * 384 + b * 128 + i] = acc;
  if (b == 0) {
    const float* pwo = proj_w + o * 384;
    float s = (pwo[i] + pwo[i + 128] + pwo[i + 256]) * mlp_b[i];
    #pragma unroll
    for (int sh = 1; sh <= 32; sh <<= 1) s += __shfl_xor(s, sh, 64);
    __shared__ float r2[2];
    if ((i & 63) == 0) r2[i >> 6] = s;
    __syncthreads();
    if (i == 0) bc[o] = r2[0] + r2[1];
  }
}

// ---------------------------------------------------------------------------
// Fused depthwise 3x3 + 5x5, coalesced float4 staging.
// Grid (384 c, 8 ty): same-channel strips share fl mod 8 -> same XCD ->
// halo rows hit that XCD's L2 instead of refetching from HBM.
// ---------------------------------------------------------------------------
__global__ __launch_bounds__(256) void k_dwf(
    const float* __restrict__ in, const float* __restrict__ w3,
    const float* __restrict__ w5, float* __restrict__ out3,
    float* __restrict__ out5)
{
  const int c  = blockIdx.x;          // 0..383
  const int ty = blockIdx.y;          // 0..7
  const int y0 = ty * 16;
  __shared__ float tS[20][136];
  const float* ip = in + (size_t)c * P;

  if (threadIdx.x < 20) {             // x = -2,-1,128,129 are never in-image
    tS[threadIdx.x][0] = 0.f; tS[threadIdx.x][1] = 0.f;
    tS[threadIdx.x][130] = 0.f; tS[threadIdx.x][131] = 0.f;
  }
  for (int e = threadIdx.x; e < 640; e += 256) {
    const int r = e >> 5, q = e & 31;
    const int gy = y0 + r - 2;
    float4 v = make_float4(0.f, 0.f, 0.f, 0.f);
    if (gy >= 0 && gy < 128) v = *(const float4*)&ip[gy * 128 + q * 4];
    *(float4*)&tS[r][2 + q * 4] = v;
  }
  __syncthreads();

  float a3[9], a5[25];
  #pragma unroll
  for (int i = 0; i < 9; ++i)  a3[i] = w3[c * 9 + i];
  #pragma unroll
  for (int i = 0; i < 25; ++i) a5[i] = w5[c * 25 + i];

  const int py  = threadIdx.x >> 4;           // 0..15
  const int px0 = (threadIdx.x & 15) * 8;     // 0..120
  float o3[8] = {}, o5[8] = {};
  #pragma unroll
  for (int r = 0; r < 5; ++r) {
    float4 sa = *(const float4*)&tS[py + r][px0];
    float4 sb = *(const float4*)&tS[py + r][px0 + 4];
    float4 sc = *(const float4*)&tS[py + r][px0 + 8];
    const float s[12] = {sa.x, sa.y, sa.z, sa.w, sb.x, sb.y, sb.z, sb.w,
                         sc.x, sc.y, sc.z, sc.w};
    #pragma unroll
    for (int j = 0; j < 8; ++j) {
      float acc = a5[r * 5 + 0] * s[j];
      #pragma unroll
      for (int d = 1; d < 5; ++d) acc += a5[r * 5 + d] * s[j + d];
      o5[j] += acc;
    }
    if (r >= 1 && r <= 3) {
      #pragma unroll
      for (int j = 0; j < 8; ++j) {
        float b = a3[(r - 1) * 3 + 0] * s[j + 1];
        b += a3[(r - 1) * 3 + 1] * s[j + 2];
        b += a3[(r - 1) * 3 + 2] * s[j + 3];
        o3[j] += b;
      }
    }
  }
  const size_t ob = (size_t)c * P + (y0 + py) * 128 + px0;
  float4* p3 = (float4*)&out3[ob];
  float4* p5 = (float4*)&out5[ob];
  p3[0] = make_float4(o3[0], o3[1], o3[2], o3[3]);
  p3[1] = make_float4(o3[4], o3[5], o3[6], o3[7]);
  p5[0] = make_float4(o5[0], o5[1], o5[2], o5[3]);
  p5[1] = make_float4(o5[4], o5[5], o5[6], o5[7]);
}

// ---------------------------------------------------------------------------
// Grouped pointwise (12 groups of 32->32), both branches in one launch.
// ---------------------------------------------------------------------------
__global__ __launch_bounds__(256) void k_pw2(
    const float* in0, const float* __restrict__ w0, float* out0,
    const float* in1, const float* __restrict__ w1, float* out1)
{
  const float* in = blockIdx.z ? in1 : in0;
  const float* w  = blockIdx.z ? w1 : w0;
  float*      out = blockIdx.z ? out1 : out0;
  const int g = blockIdx.y;
  const int p = blockIdx.x * 256 + threadIdx.x;
  __shared__ float wL[1024];
  for (int e = threadIdx.x; e < 1024; e += 256) wL[e] = w[g * 1024 + e];
  __syncthreads();
  float r[32];
  #pragma unroll
  for (int i = 0; i < 32; ++i) r[i] = in[(g * 32 + i) * P + p];
  #pragma unroll
  for (int o = 0; o < 32; ++o) {
    float acc = 0.f;
    #pragma unroll
    for (int i = 0; i < 32; ++i) acc += wL[o * 32 + i] * r[i];
    out[(g * 32 + o) * P + p] = acc;
  }
}

// ---------------------------------------------------------------------------
// Top-4: one wave per query window; butterfly argmax (lowest-index ties).
// ---------------------------------------------------------------------------
__global__ __launch_bounds__(256) void k_topk(
    const float* __restrict__ qwin, const float* __restrict__ kwin,
    int* __restrict__ ridx)
{
  const int b = blockIdx.y;
  const int i = blockIdx.x * 4 + (threadIdx.x >> 6);
  const int j = threadIdx.x & 63;
  const float4* q4 = (const float4*)&qwin[(b * 64 + i) * 128];
  const float4* k4 = (const float4*)&kwin[(b * 64 + j) * 128];
  float v = 0.f;
  #pragma unroll
  for (int t = 0; t < 32; ++t) {
    float4 a = q4[t], c = k4[t];
    v += a.x * c.x + a.y * c.y + a.z * c.z + a.w * c.w;
  }
  int res[4];
  #pragma unroll
  for (int r = 0; r < 4; ++r) {
    float bv = v; int bj = j;
    #pragma unroll
    for (int s = 1; s < 64; s <<= 1) {
      const float ov = __shfl_xor(bv, s, 64);
      const int   oj = __shfl_xor(bj, s, 64);
      if (ov > bv || (ov == bv && oj < bj)) { bv = ov; bj = oj; }
    }
    res[r] = bj;
    if (j == bj) v = -INFINITY;
  }
  if (j == 0)
    *(int4*)&ridx[(b * 64 + i) * 4] = make_int4(res[0], res[1], res[2], res[3]);
}

// ---------------------------------------------------------------------------
// Repack v2: window-PAIR blocks (512 thr) for full 128B line utilization.
// Thread t: row = t>>5, x = t&31 -> win = x>>4, key = row*16 + (x&15).
// K/Q reads: 128B-contiguous rows spanning both windows. V: per-row float4
// reads, win = t&1 interleave pairs lanes on each 128B line. Write formulas
// (kd/qd/vd layouts + swizzles) byte-identical to validated version.
// Window maxes: q/k kept in regs; 4 redS phases (q,k x win0,win1), exact fmax.
// ---------------------------------------------------------------------------
__global__ __launch_bounds__(512) void k_repack(
    const float* __restrict__ e0, const float* __restrict__ e1,
    const float* __restrict__ e2, unsigned int* __restrict__ kvimg,
    unsigned int* __restrict__ qimg, float* __restrict__ qwin,
    float* __restrict__ kwin)
{
  const int fl = blockIdx.x + 32 * (blockIdx.y + 4 * blockIdx.z); // 0..383
  const int nf = (fl & 7) * 48 + (fl >> 3);      // bijective: 384 = 8*48
  const int wp = nf & 31, h = (nf >> 5) & 3, b = nf >> 7;
  const float* e = (b == 0) ? e0 : ((b == 1) ? e1 : e2);
  const int w0 = wp * 2;                          // wx0 even -> w0,w0+1 same row
  const int wy = w0 >> 3, wx0 = w0 & 7;
  const int jbase0 = (wy * 16) * 128 + wx0 * 16;
  const int t = threadIdx.x;

  __shared__ float redS[32][257];
  __shared__ float part[16][32];

  float qreg[32], kreg[32];

  // ---- K + Q ----
  const int row = t >> 5, x = t & 31;
  const int win = x >> 4, key = row * 16 + (x & 15);
  {
    const int hw = jbase0 + row * 128 + x;
    const float* eK = e + (size_t)(128 + h * 32) * P + hw;
    const float* eQ = e + (size_t)(h * 32) * P + hw;
    const int half = key >> 7, kl = key & 127;
    unsigned int* kd = kvimg + (size_t)((b * 4 + h) * 64 + w0 + win) * 8192
                       + half * 4096 + kl * 16;
    unsigned int* qd = qimg + (size_t)((b * 4 + h) * 64 + w0 + win) * 4096
                       + key * 16;
    #pragma unroll
    for (int dd = 0; dd < 16; ++dd) {
      float k0 = eK[(size_t)(2 * dd) * P], k1 = eK[(size_t)(2 * dd + 1) * P];
      kreg[2 * dd] = k0; kreg[2 * dd + 1] = k1;
      kd[dd ^ ((kl & 3) << 2)] = packbf(k0, k1);
      float q0 = eQ[(size_t)(2 * dd) * P], q1 = eQ[(size_t)(2 * dd + 1) * P];
      qreg[2 * dd] = q0; qreg[2 * dd + 1] = q1;
      qd[dd] = packbf(q0 * QSCALE, q1 * QSCALE);
    }
  }
  // ---- V: thread (vwin = t&1, half, d, q4); 2 rows x 4 float4 reads ----
  {
    const int vwin = t & 1, r = t >> 1;
    const int half = r >> 7, d = (r & 127) >> 2, q4 = r & 3;
    const int R = 8 * half + 2 * q4;
    const float* eV = e + (size_t)(256 + h * 32 + d) * P + jbase0 + vwin * 16;
    float rv[2][16];
    #pragma unroll
    for (int rr = 0; rr < 2; ++rr) {
      const float4* src = (const float4*)&eV[(R + rr) * 128];
      #pragma unroll
      for (int i = 0; i < 4; ++i) {
        float4 v = src[i];
        rv[rr][4*i] = v.x; rv[rr][4*i+1] = v.y;
        rv[rr][4*i+2] = v.z; rv[rr][4*i+3] = v.w;
      }
    }
    unsigned int* vd = kvimg + (size_t)((b * 4 + h) * 64 + w0 + vwin) * 8192
                       + half * 4096 + 2048 + d * 64;
    #pragma unroll
    for (int j = 0; j < 16; ++j) {
      const int kp2 = q4 * 16 + j;
      const int rr = j >> 3, pp = (j & 7) * 2;
      vd[kp2 ^ ((d & 7) << 2)] = packbf(rv[rr][pp], rv[rr][pp + 1]);
    }
  }
  // ---- window maxes: 4 phases (q win0, q win1, k win0, k win1) ----
  #pragma unroll
  for (int ph = 0; ph < 4; ++ph) {
    const int pwv = ph & 1;
    const bool isq = ph < 2;
    __syncthreads();
    if (win == pwv) {
      #pragma unroll
      for (int ch = 0; ch < 32; ++ch)
        redS[ch][key] = isq ? qreg[ch] : kreg[ch];
    }
    __syncthreads();
    {
      const int ch = t & 31, seg = t >> 5;       // 16 segs x 16 px
      float mx = redS[ch][seg * 16];
      #pragma unroll
      for (int i = 1; i < 16; ++i) mx = fmaxf(mx, redS[ch][seg * 16 + i]);
      part[seg][ch] = mx;
    }
    __syncthreads();
    if (t < 32) {
      float mx = part[0][t];
      #pragma unroll
      for (int s = 1; s < 16; ++s) mx = fmaxf(mx, part[s][t]);
      float* dst = isq ? qwin : kwin;
      dst[(size_t)(b * 64 + w0 + pwv) * 128 + h * 32 + t] = mx;
    }
  }
}

// ---------------------------------------------------------------------------
// MFMA flash attention (frozen round-10/12 form).
// ---------------------------------------------------------------------------
__global__ __launch_bounds__(512, 4) void k_attn_mfma(
    const unsigned int* __restrict__ kvimg, const unsigned int* __restrict__ qimg,
    const int* __restrict__ ridx, float* __restrict__ attnch)
{
  const int fl = blockIdx.x + 64 * (blockIdx.y + 4 * blockIdx.z);
  const int nf = (fl & 7) * 96 + (fl >> 3);       // bijective XCD swizzle
  const int w = nf & 63, h = (nf >> 6) & 3, b = nf >> 8;
  const int tid = threadIdx.x;
  const int wv = tid >> 6, lane = tid & 63;
  const int qi = lane & 15, g = lane >> 4;
  const int wy = w >> 3, wx = w & 7;

  __shared__ __align__(16) unsigned int kvbuf[2][4096];   // 2 x 16KB

  const unsigned int* kwin = kvimg + (size_t)((b * 4 + h) * 64) * 8192;
  const unsigned int* qwin = qimg + (size_t)((b * 4 + h) * 64 + w) * 4096;

  // Q fragments: lane (qi,g), tile s: Q[q=(wv*2+s)*16+qi][d=8g..8g+7]
  bf16x8 qv[2];
  #pragma unroll
  for (int s = 0; s < 2; ++s) {
    union { uint4 u; bf16x8 v; } tq;
    tq.u = *(const uint4*)(qwin + ((wv * 2 + s) * 16 + qi) * 16 + g * 4);
    qv[s] = tq.v;
  }
  const int4 jv = *(const int4*)(ridx + (b * 64 + w) * 4);
  const int ja[4] = {jv.x, jv.y, jv.z, jv.w};

  const f32x4 fz = {0.f, 0.f, 0.f, 0.f};
  float m[2], l[2];
  f32x4 acc[2][2];
  #pragma unroll
  for (int s = 0; s < 2; ++s) {
    m[s] = -3.0e38f; l[s] = 0.f; acc[s][0] = fz; acc[s][1] = fz;
  }

  // prologue: load chunk 0 into regs
  uint4 st0, st1;
  {
    const uint4* s4 = (const uint4*)(kwin + (size_t)ja[0] * 8192);
    st0 = s4[tid]; st1 = s4[512 + tid];
  }

#define SOFTMAX_PACK(SC, S, PB) {                                           \
    float wmax = -3.0e38f;                                                  \
    _Pragma("unroll") for (int c = 0; c < 4; ++c)                           \
      _Pragma("unroll") for (int u = 0; u < 2; ++u)                         \
        _Pragma("unroll") for (int t2 = 0; t2 < 4; ++t2)                    \
          wmax = fmaxf(wmax, SC[c][u][t2]);                                 \
    wmax = fmaxf(wmax, __shfl_xor(wmax, 16, 64));                           \
    wmax = fmaxf(wmax, __shfl_xor(wmax, 32, 64));                           \
    const float mnew = fmaxf(m[S], wmax);                                   \
    const float corr = EXP2F(m[S] - mnew);                                  \
    m[S] = mnew;                                                            \
    acc[S][0] *= corr; acc[S][1] *= corr;                                   \
    float psum = 0.f;                                                       \
    _Pragma("unroll") for (int c = 0; c < 4; ++c)                           \
      _Pragma("unroll") for (int u = 0; u < 2; ++u) {                       \
        const float p0 = EXP2F(SC[c][u][0] - mnew);                         \
        const float p1 = EXP2F(SC[c][u][1] - mnew);                         \
        const float p2 = EXP2F(SC[c][u][2] - mnew);                         \
        const float p3 = EXP2F(SC[c][u][3] - mnew);                         \
        psum += (p0 + p1) + (p2 + p3);                                      \
        PB[c][2 * u]     = pk2(p0, p1);                                     \
        PB[c][2 * u + 1] = pk2(p2, p3);                                     \
      }                                                                     \
    l[S] = l[S] * corr + psum;                                              \
  }

  for (int ch = 0; ch < 8; ++ch) {
    // write chunk ch (staged in regs) into buf[ch&1]
    {
      uint4* d4 = (uint4*)kvbuf[ch & 1];
      d4[tid] = st0; d4[512 + tid] = st1;
    }
    // issue chunk ch+1 loads — latency hides under this chunk's compute
    if (ch < 7) {
      const int nx = ch + 1;
      const uint4* s4 = (const uint4*)(kwin + (size_t)ja[nx >> 1] * 8192
                                       + (size_t)(nx & 1) * 4096);
      st0 = s4[tid]; st1 = s4[512 + tid];
    }
    __syncthreads();   // chunk ch visible; prior chunk's readers are done

    const unsigned int* bc = kvbuf[ch & 1];
    const bf16x8* kp = (const bf16x8*)bc;
    const unsigned short* vsh = (const unsigned short*)(bc + 2048);

    f32x4 scA[4][2], scB[4][2];
    __builtin_amdgcn_s_setprio(1);
    #pragma unroll
    for (int c = 0; c < 4; ++c) {
      #pragma unroll
      for (int u = 0; u < 2; ++u) {
        const int key = 32 * c + 8 * (qi >> 2) + 4 * u + (qi & 3);
        const bf16x8 ka = kp[key * 4 + (g ^ (qi & 3))];
        scA[c][u] = __builtin_amdgcn_mfma_f32_16x16x32_bf16(ka, qv[0], fz, 0, 0, 0);
        scB[c][u] = __builtin_amdgcn_mfma_f32_16x16x32_bf16(ka, qv[1], fz, 0, 0, 0);
      }
    }
    __builtin_amdgcn_s_setprio(0);
    unsigned int pbA[4][4], pbB[4][4];
    SOFTMAX_PACK(scA, 0, pbA);
    SOFTMAX_PACK(scB, 1, pbB);
    __builtin_amdgcn_s_setprio(1);
    #pragma unroll
    for (int c = 0; c < 4; ++c) {
      #pragma unroll
      for (int dt = 0; dt < 2; ++dt) {
        const int d0 = dt * 16 + qi;
        const bf16x8 va = *(const bf16x8*)&vsh[
            (unsigned)((d0 * 128 + 32 * c + 8 * g) ^ ((d0 & 7) << 3))];
        union { unsigned int u4[4]; bf16x8 v; } pva, pvb;
        pva.u4[0] = pbA[c][0]; pva.u4[1] = pbA[c][1];
        pva.u4[2] = pbA[c][2]; pva.u4[3] = pbA[c][3];
        pvb.u4[0] = pbB[c][0]; pvb.u4[1] = pbB[c][1];
        pvb.u4[2] = pbB[c][2]; pvb.u4[3] = pbB[c][3];
        acc[0][dt] = __builtin_amdgcn_mfma_f32_16x16x32_bf16(va, pva.v, acc[0][dt], 0, 0, 0);
        acc[1][dt] = __builtin_amdgcn_mfma_f32_16x16x32_bf16(va, pvb.v, acc[1][dt], 0, 0, 0);
      }
    }
    __builtin_amdgcn_s_setprio(0);
  }
#undef SOFTMAX_PACK

  // epilogue: lane (qi,g) holds O^T[d = dt*16+4g+t][q = (wv*2+s)*16+qi]
  #pragma unroll
  for (int s = 0; s < 2; ++s) {
    float lsum = l[s];
    lsum += __shfl_xor(lsum, 16, 64);
    lsum += __shfl_xor(lsum, 32, 64);
    const float inv = 1.f / lsum;
    const int hwq = (wy * 16 + wv * 2 + s) * 128 + wx * 16 + qi;
    #pragma unroll
    for (int dt = 0; dt < 2; ++dt)
      #pragma unroll
      for (int t = 0; t < 4; ++t) {
        const int d = dt * 16 + 4 * g + t;
        attnch[(size_t)(b * 128 + h * 32 + d) * P + hwq] = acc[s][dt][t] * inv;
      }
  }
}

// ---------------------------------------------------------------------------
extern "C" void kernel_launch(void* const* d_in, const int* in_sizes, int n_in,
                              void* d_out, int out_size, void* d_ws, size_t ws_size,
                              hipStream_t stream)
{
  (void)in_sizes; (void)n_in; (void)out_size;
  const float* x      = (const float*)d_in[0];
  const float* qkv2_w = (const float*)d_in[1];
  const float* dw3_w  = (const float*)d_in[2];
  const float* pw3_w  = (const float*)d_in[3];
  const float* dw5_w  = (const float*)d_in[4];
  const float* pw5_w  = (const float*)d_in[5];
  const float* mlp_w  = (const float*)d_in[6];
  const float* mlp_b  = (const float*)d_in[7];
  const float* proj_w = (const float*)d_in[8];
  const float* ln_g   = (const float*)d_in[9];
  const float* ln_b   = (const float*)d_in[10];

  float* ws = (float*)d_ws;
  const size_t CH = (size_t)384 * P;
  // region liveness:
  //  ws+0   : qkv (fp32)
  //  ws+CH  : dwt3 (dw3 out)        -> qimg (bf16, after repack)
  //  ws+2CH : y3                    -> attnch
  //  ws+3CH : dwt5/y5 (pw in-place)
  //  ws+4CH : kvimg (bf16, 25.2MB)
  //  ws+5CH : qwin | kwin | ridx | Wc | bc
  float* qkv    = ws;
  float* dwt3   = ws + CH;
  float* y3     = ws + 2 * CH;
  float* y5     = ws + 3 * CH;           // also dwt5 (in-place pw5)
  float* qwin   = ws + 5 * CH;
  float* kwin   = qwin + 3 * 64 * 128;
  int*   ridx   = (int*)(kwin + 3 * 64 * 128);
  float* Wc     = (float*)(ridx + 768);
  float* bc     = Wc + 128 * 384;
  unsigned int* kvimg = (unsigned int*)(ws + 4 * CH);
  unsigned int* qimg  = (unsigned int*)dwt3;
  float* attnch = y3;
  (void)ws_size;

  // fold mlp into proj (independent of main chain)
  k_fold<<<dim3(128, 3), 128, 0, stream>>>(proj_w, mlp_w, mlp_b, Wc, bc);

  // qkv: 64oc x 128px tiles -> 768 blocks (3/CU even)
  k_conv_mfma<2, 2><<<dim3(128, 6, 1), 256, 0, stream>>>(x, qkv2_w, nullptr, qkv, 128, 0, 0);
  // fused depthwise 3x3 + 5x5; grid (c, ty) so same-c strips share an XCD
  k_dwf<<<dim3(384, 8), 256, 0, stream>>>(qkv, dw3_w, dw5_w, dwt3, y5);
  // both grouped-pointwise branches in one launch
  k_pw2<<<dim3(64, 12, 2), 256, 0, stream>>>(dwt3, pw3_w, y3, y5, pw5_w, y5);
  // repack v2 (window-pair) + fused window max
  k_repack<<<dim3(32, 4, 3), 512, 0, stream>>>(qkv, y3, y5, kvimg, qimg, qwin, kwin);
  k_topk<<<dim3(16, 3), 256, 0, stream>>>(qwin, kwin, ridx);
  k_attn_mfma<<<dim3(64, 4, 3), 512, 0, stream>>>(kvimg, qimg, ridx, attnch);
  // fused mlp+proj+LayerNorm: 128oc x 64px blocks, writes d_out directly
  k_projln<<<dim3(256), 256, 0, stream>>>(attnch, Wc, bc, ln_g, ln_b, (float*)d_out);
}

// Round 15
// 184.590 us; speedup vs baseline: 1.0064x; 1.0064x over previous
//
#include <hip/hip_runtime.h>
#include <math.h>

#define P 16384               // 128*128 pixels
#define SCALEF 0.08838834764831845f             // 128^-0.5
#define QSCALE 0.12752075616290145f             // SCALEF * log2(e)

typedef short bf16x8 __attribute__((ext_vector_type(8)));
typedef float f32x4 __attribute__((ext_vector_type(4)));

// pack two f32 -> bf16 pair in ONE VALU (RNE) — same rounding as the old
// bit-twiddled packbf, so outputs are bit-identical where swapped in.
__device__ __forceinline__ unsigned int pk2(float a, float b) {
  unsigned int r;
  asm("v_cvt_pk_bf16_f32 %0, %1, %2" : "=v"(r) : "v"(a), "v"(b));
  return r;
}
#define EXP2F(x) __builtin_amdgcn_exp2f(x)

// ---------------------------------------------------------------------------
// Split-bf16 MFMA GEMM for 1x1 conv: out[oc][p] = sum_ic w[oc][ic]*in[ic][p].
// NS=2: x=H+L, 3 terms (err ~1e-5 rel). Block: 64 oc x JT*64 px, 4 waves.
// ---------------------------------------------------------------------------
template<int NS, int JT>
__global__ __launch_bounds__(256) void k_conv_mfma(
    const float* __restrict__ in, const float* __restrict__ w,
    const float* __restrict__ bias, float* __restrict__ out,
    const int IC, const int in_zstr, const int out_zstr)
{
  const int p0  = blockIdx.x * (JT * 64);
  const int oc0 = blockIdx.y * 64;
  in  += (size_t)blockIdx.z * (size_t)in_zstr;
  out += (size_t)blockIdx.z * (size_t)out_zstr;
  const int tid = threadIdx.x;
  const int wv = tid >> 6;
  const int lane = tid & 63;
  const int qi = lane & 15, g = lane >> 4;

  __shared__ __align__(16) unsigned int bS[NS][JT * 64 * 16];
  __shared__ __align__(16) unsigned int aS[NS][64 * 16];

  const f32x4 fz = {0.f, 0.f, 0.f, 0.f};
  f32x4 acc[JT][4];
  #pragma unroll
  for (int j = 0; j < JT; ++j)
    #pragma unroll
    for (int o = 0; o < 4; ++o) acc[j][o] = fz;

  for (int k0 = 0; k0 < IC; k0 += 32) {
    __syncthreads();
    // ---- stage B: thread = k-pair (tid>>4), JT*4 px starting (tid&15)*JT*4
    {
      const int kB = tid >> 4;
      const int pB = (tid & 15) * (JT * 4);
      const float* r0 = in + (size_t)(k0 + 2 * kB) * P + p0 + pB;
      #pragma unroll
      for (int half = 0; half < JT / 2; ++half) {
        float x0[8], x1[8];
        #pragma unroll
        for (int v = 0; v < 2; ++v) {
          float4 a = ((const float4*)r0)[half * 2 + v];
          float4 c = ((const float4*)(r0 + P))[half * 2 + v];
          x0[4*v] = a.x; x0[4*v+1] = a.y; x0[4*v+2] = a.z; x0[4*v+3] = a.w;
          x1[4*v] = c.x; x1[4*v+1] = c.y; x1[4*v+2] = c.z; x1[4*v+3] = c.w;
        }
        #pragma unroll
        for (int ii = 0; ii < 8; ++ii) {
          const int i8 = (ii + tid) & 7;           // bank rotation
          const int i = half * 8 + i8;
          const unsigned idx = (unsigned)((pB + i) * 16 + (kB ^ ((i & 3) << 2)));
          const unsigned u0 = __float_as_uint(x0[i8]);
          const unsigned u1 = __float_as_uint(x1[i8]);
          bS[0][idx] = __builtin_amdgcn_perm(u1, u0, 0x07060302u);
          const float r0f = x0[i8] - __uint_as_float(u0 & 0xffff0000u);
          const float r1f = x1[i8] - __uint_as_float(u1 & 0xffff0000u);
          bS[1][idx] = pk2(r0f, r1f);
        }
      }
    }
    // ---- stage A: thread = oc row tid>>2, k span (tid&3)*8 ----
    {
      const int oA = tid >> 2;
      const int kA = (tid & 3) * 8;
      const float* rw = w + (size_t)(oc0 + oA) * IC + k0 + kA;
      float4 wa = ((const float4*)rw)[0];
      float4 wb = ((const float4*)rw)[1];
      float y[8] = {wa.x, wa.y, wa.z, wa.w, wb.x, wb.y, wb.z, wb.w};
      #pragma unroll
      for (int i = 0; i < 4; ++i) {
        const int dd = (kA >> 1) + i;
        const unsigned idx = (unsigned)(oA * 16 + (dd ^ ((oA & 3) << 2)));
        const unsigned u0 = __float_as_uint(y[2*i]);
        const unsigned u1 = __float_as_uint(y[2*i+1]);
        aS[0][idx] = __builtin_amdgcn_perm(u1, u0, 0x07060302u);
        const float r0f = y[2*i]   - __uint_as_float(u0 & 0xffff0000u);
        const float r1f = y[2*i+1] - __uint_as_float(u1 & 0xffff0000u);
        aS[1][idx] = pk2(r0f, r1f);
      }
    }
    __syncthreads();

    bf16x8 aF[4][NS];
    #pragma unroll
    for (int o = 0; o < 4; ++o) {
      const unsigned ab = (unsigned)((o * 16 + qi) * 16 + 4 * (g ^ (qi & 3)));
      #pragma unroll
      for (int s = 0; s < NS; ++s)
        aF[o][s] = *(const bf16x8*)&aS[s][ab];
    }
    #pragma unroll
    for (int j = 0; j < JT; ++j) {
      const unsigned bb = (unsigned)(((wv * JT + j) * 16 + qi) * 16 + 4 * (g ^ (qi & 3)));
      const bf16x8 b0 = *(const bf16x8*)&bS[0][bb];
      const bf16x8 b1 = *(const bf16x8*)&bS[1][bb];
      #pragma unroll
      for (int o = 0; o < 4; ++o) {
        acc[j][o] = __builtin_amdgcn_mfma_f32_16x16x32_bf16(aF[o][0], b0, acc[j][o], 0, 0, 0);
        acc[j][o] = __builtin_amdgcn_mfma_f32_16x16x32_bf16(aF[o][0], b1, acc[j][o], 0, 0, 0);
        acc[j][o] = __builtin_amdgcn_mfma_f32_16x16x32_bf16(aF[o][1], b0, acc[j][o], 0, 0, 0);
      }
    }
  }

  float bv[4][4];
  #pragma unroll
  for (int o = 0; o < 4; ++o)
    #pragma unroll
    for (int t = 0; t < 4; ++t)
      bv[o][t] = bias ? bias[oc0 + o * 16 + 4 * g + t] : 0.f;

  #pragma unroll
  for (int j = 0; j < JT; ++j) {
    const int px = p0 + (wv * JT + j) * 16 + qi;
    #pragma unroll
    for (int o = 0; o < 4; ++o)
      #pragma unroll
      for (int t = 0; t < 4; ++t)
        out[(size_t)(oc0 + o * 16 + 4 * g + t) * P + px] = acc[j][o][t] + bv[o][t];
  }
}

// ---------------------------------------------------------------------------
// Fused mlp+proj GEMM (IC=384) + LayerNorm epilogue -> writes d_out directly.
// ---------------------------------------------------------------------------
__global__ __launch_bounds__(256) void k_projln(
    const float* __restrict__ in, const float* __restrict__ w,
    const float* __restrict__ bias, const float* __restrict__ ln_g,
    const float* __restrict__ ln_b, float* __restrict__ out)
{
  const int p0 = blockIdx.x * 64;
  const int tid = threadIdx.x;
  const int wv = tid >> 6;
  const int lane = tid & 63;
  const int qi = lane & 15, g = lane >> 4;

  __shared__ __align__(16) unsigned int bS[2][64 * 16];
  __shared__ __align__(16) unsigned int aS[2][128 * 16];

  const f32x4 fz = {0.f, 0.f, 0.f, 0.f};
  f32x4 acc[8];
  #pragma unroll
  for (int o = 0; o < 8; ++o) acc[o] = fz;

  for (int k0 = 0; k0 < 384; k0 += 32) {
    __syncthreads();
    // stage B: thread = k-pair (tid>>4), 4 px at (tid&15)*4
    {
      const int kB = tid >> 4;
      const int pB = (tid & 15) * 4;
      const float* r0 = in + (size_t)(k0 + 2 * kB) * P + p0 + pB;
      float4 a = *(const float4*)r0;
      float4 c = *(const float4*)(r0 + P);
      const float x0[4] = {a.x, a.y, a.z, a.w};
      const float x1[4] = {c.x, c.y, c.z, c.w};
      #pragma unroll
      for (int i = 0; i < 4; ++i) {
        const unsigned idx = (unsigned)((pB + i) * 16 + (kB ^ (i << 2)));
        const unsigned u0 = __float_as_uint(x0[i]);
        const unsigned u1 = __float_as_uint(x1[i]);
        bS[0][idx] = __builtin_amdgcn_perm(u1, u0, 0x07060302u);
        const float r0f = x0[i] - __uint_as_float(u0 & 0xffff0000u);
        const float r1f = x1[i] - __uint_as_float(u1 & 0xffff0000u);
        bS[1][idx] = pk2(r0f, r1f);
      }
    }
    // stage A: thread = oc row (tid>>1), k span (tid&1)*16
    {
      const int oA = tid >> 1;
      const int kA = (tid & 1) * 16;
      const float* rw = w + (size_t)oA * 384 + k0 + kA;
      float4 wa = ((const float4*)rw)[0];
      float4 wb = ((const float4*)rw)[1];
      float4 wc = ((const float4*)rw)[2];
      float4 wd = ((const float4*)rw)[3];
      const float y[16] = {wa.x, wa.y, wa.z, wa.w, wb.x, wb.y, wb.z, wb.w,
                           wc.x, wc.y, wc.z, wc.w, wd.x, wd.y, wd.z, wd.w};
      #pragma unroll
      for (int i = 0; i < 8; ++i) {
        const int dd = (kA >> 1) + i;
        const unsigned idx = (unsigned)(oA * 16 + (dd ^ ((oA & 3) << 2)));
        const unsigned u0 = __float_as_uint(y[2*i]);
        const unsigned u1 = __float_as_uint(y[2*i+1]);
        aS[0][idx] = __builtin_amdgcn_perm(u1, u0, 0x07060302u);
        const float r0f = y[2*i]   - __uint_as_float(u0 & 0xffff0000u);
        const float r1f = y[2*i+1] - __uint_as_float(u1 & 0xffff0000u);
        aS[1][idx] = pk2(r0f, r1f);
      }
    }
    __syncthreads();

    const unsigned bb = (unsigned)((wv * 16 + qi) * 16 + 4 * (g ^ (qi & 3)));
    const bf16x8 b0 = *(const bf16x8*)&bS[0][bb];
    const bf16x8 b1 = *(const bf16x8*)&bS[1][bb];
    #pragma unroll
    for (int o = 0; o < 8; ++o) {
      const unsigned ab = (unsigned)((o * 16 + qi) * 16 + 4 * (g ^ (qi & 3)));
      const bf16x8 a0 = *(const bf16x8*)&aS[0][ab];
      const bf16x8 a1 = *(const bf16x8*)&aS[1][ab];
      acc[o] = __builtin_amdgcn_mfma_f32_16x16x32_bf16(a0, b0, acc[o], 0, 0, 0);
      acc[o] = __builtin_amdgcn_mfma_f32_16x16x32_bf16(a0, b1, acc[o], 0, 0, 0);
      acc[o] = __builtin_amdgcn_mfma_f32_16x16x32_bf16(a1, b0, acc[o], 0, 0, 0);
    }
  }

  // epilogue: bias + LayerNorm over the 128 channels of pixel px
  const int px = p0 + wv * 16 + qi;
  float vch[8][4];
  float sum = 0.f, sq = 0.f;
  #pragma unroll
  for (int o = 0; o < 8; ++o)
    #pragma unroll
    for (int t = 0; t < 4; ++t) {
      const float v = acc[o][t] + bias[o * 16 + 4 * g + t];
      vch[o][t] = v; sum += v; sq += v * v;
    }
  sum += __shfl_xor(sum, 16, 64); sum += __shfl_xor(sum, 32, 64);
  sq  += __shfl_xor(sq, 16, 64);  sq  += __shfl_xor(sq, 32, 64);
  const float mu = sum * (1.f / 128.f);
  const float var = sq * (1.f / 128.f) - mu * mu;
  const float rs = rsqrtf(var + 1e-5f);
  #pragma unroll
  for (int o = 0; o < 8; ++o)
    #pragma unroll
    for (int t = 0; t < 4; ++t) {
      const int oc = o * 16 + 4 * g + t;
      out[(size_t)oc * P + px] = (vch[o][t] - mu) * rs * ln_g[oc] + ln_b[oc];
    }
}

// ---------------------------------------------------------------------------
// Fold mlp into proj (Wc = proj_w x blockdiag(mlp_w), bc = proj_w x mlp_b).
// ---------------------------------------------------------------------------
__global__ __launch_bounds__(128) void k_fold(
    const float* __restrict__ proj_w, const float* __restrict__ mlp_w,
    const float* __restrict__ mlp_b, float* __restrict__ Wc,
    float* __restrict__ bc)
{
  const int o = blockIdx.x;      // 0..127
  const int b = blockIdx.y;      // 0..2
  const int i = threadIdx.x;     // 0..127
  const float* pw = proj_w + o * 384 + b * 128;
  float acc = 0.f;
  for (int j = 0; j < 128; ++j)
    acc += pw[j] * mlp_w[j * 128 + i];
  Wc[o * 384 + b * 128 + i] = acc;
  if (b == 0) {
    const float* pwo = proj_w + o * 384;
    float s = (pwo[i] + pwo[i + 128] + pwo[i + 256]) * mlp_b[i];
    #pragma unroll
    for (int sh = 1; sh <= 32; sh <<= 1) s += __shfl_xor(s, sh, 64);
    __shared__ float r2[2];
    if ((i & 63) == 0) r2[i >> 6] = s;
    __syncthreads();
    if (i == 0) bc[o] = r2[0] + r2[1];
  }
}

// ---------------------------------------------------------------------------
// Fused depthwise 3x3 + 5x5, coalesced float4 staging.
// ---------------------------------------------------------------------------
__global__ __launch_bounds__(256) void k_dwf(
    const float* __restrict__ in, const float* __restrict__ w3,
    const float* __restrict__ w5, float* __restrict__ out3,
    float* __restrict__ out5)
{
  const int c  = blockIdx.x;          // 0..383
  const int ty = blockIdx.y;          // 0..7
  const int y0 = ty * 16;
  __shared__ float tS[20][136];
  const float* ip = in + (size_t)c * P;

  if (threadIdx.x < 20) {             // x = -2,-1,128,129 are never in-image
    tS[threadIdx.x][0] = 0.f; tS[threadIdx.x][1] = 0.f;
    tS[threadIdx.x][130] = 0.f; tS[threadIdx.x][131] = 0.f;
  }
  for (int e = threadIdx.x; e < 640; e += 256) {
    const int r = e >> 5, q = e & 31;
    const int gy = y0 + r - 2;
    float4 v = make_float4(0.f, 0.f, 0.f, 0.f);
    if (gy >= 0 && gy < 128) v = *(const float4*)&ip[gy * 128 + q * 4];
    *(float4*)&tS[r][2 + q * 4] = v;
  }
  __syncthreads();

  float a3[9], a5[25];
  #pragma unroll
  for (int i = 0; i < 9; ++i)  a3[i] = w3[c * 9 + i];
  #pragma unroll
  for (int i = 0; i < 25; ++i) a5[i] = w5[c * 25 + i];

  const int py  = threadIdx.x >> 4;           // 0..15
  const int px0 = (threadIdx.x & 15) * 8;     // 0..120
  float o3[8] = {}, o5[8] = {};
  #pragma unroll
  for (int r = 0; r < 5; ++r) {
    float4 sa = *(const float4*)&tS[py + r][px0];
    float4 sb = *(const float4*)&tS[py + r][px0 + 4];
    float4 sc = *(const float4*)&tS[py + r][px0 + 8];
    const float s[12] = {sa.x, sa.y, sa.z, sa.w, sb.x, sb.y, sb.z, sb.w,
                         sc.x, sc.y, sc.z, sc.w};
    #pragma unroll
    for (int j = 0; j < 8; ++j) {
      float acc = a5[r * 5 + 0] * s[j];
      #pragma unroll
      for (int d = 1; d < 5; ++d) acc += a5[r * 5 + d] * s[j + d];
      o5[j] += acc;
    }
    if (r >= 1 && r <= 3) {
      #pragma unroll
      for (int j = 0; j < 8; ++j) {
        float b = a3[(r - 1) * 3 + 0] * s[j + 1];
        b += a3[(r - 1) * 3 + 1] * s[j + 2];
        b += a3[(r - 1) * 3 + 2] * s[j + 3];
        o3[j] += b;
      }
    }
  }
  const size_t ob = (size_t)c * P + (y0 + py) * 128 + px0;
  float4* p3 = (float4*)&out3[ob];
  float4* p5 = (float4*)&out5[ob];
  p3[0] = make_float4(o3[0], o3[1], o3[2], o3[3]);
  p3[1] = make_float4(o3[4], o3[5], o3[6], o3[7]);
  p5[0] = make_float4(o5[0], o5[1], o5[2], o5[3]);
  p5[1] = make_float4(o5[4], o5[5], o5[6], o5[7]);
}

// ---------------------------------------------------------------------------
// Grouped pointwise (12 groups of 32->32), both branches in one launch.
// ---------------------------------------------------------------------------
__global__ __launch_bounds__(256) void k_pw2(
    const float* in0, const float* __restrict__ w0, float* out0,
    const float* in1, const float* __restrict__ w1, float* out1)
{
  const float* in = blockIdx.z ? in1 : in0;
  const float* w  = blockIdx.z ? w1 : w0;
  float*      out = blockIdx.z ? out1 : out0;
  const int g = blockIdx.y;
  const int p = blockIdx.x * 256 + threadIdx.x;
  __shared__ float wL[1024];
  for (int e = threadIdx.x; e < 1024; e += 256) wL[e] = w[g * 1024 + e];
  __syncthreads();
  float r[32];
  #pragma unroll
  for (int i = 0; i < 32; ++i) r[i] = in[(g * 32 + i) * P + p];
  #pragma unroll
  for (int o = 0; o < 32; ++o) {
    float acc = 0.f;
    #pragma unroll
    for (int i = 0; i < 32; ++i) acc += wL[o * 32 + i] * r[i];
    out[(g * 32 + o) * P + p] = acc;
  }
}

// ---------------------------------------------------------------------------
// Top-4: one wave per query window; butterfly argmax (lowest-index ties).
// ---------------------------------------------------------------------------
__global__ __launch_bounds__(256) void k_topk(
    const float* __restrict__ qwin, const float* __restrict__ kwin,
    int* __restrict__ ridx)
{
  const int b = blockIdx.y;
  const int i = blockIdx.x * 4 + (threadIdx.x >> 6);
  const int j = threadIdx.x & 63;
  const float4* q4 = (const float4*)&qwin[(b * 64 + i) * 128];
  const float4* k4 = (const float4*)&kwin[(b * 64 + j) * 128];
  float v = 0.f;
  #pragma unroll
  for (int t = 0; t < 32; ++t) {
    float4 a = q4[t], c = k4[t];
    v += a.x * c.x + a.y * c.y + a.z * c.z + a.w * c.w;
  }
  int res[4];
  #pragma unroll
  for (int r = 0; r < 4; ++r) {
    float bv = v; int bj = j;
    #pragma unroll
    for (int s = 1; s < 64; s <<= 1) {
      const float ov = __shfl_xor(bv, s, 64);
      const int   oj = __shfl_xor(bj, s, 64);
      if (ov > bv || (ov == bv && oj < bj)) { bv = ov; bj = oj; }
    }
    res[r] = bj;
    if (j == bj) v = -INFINITY;
  }
  if (j == 0)
    *(int4*)&ridx[(b * 64 + i) * 4] = make_int4(res[0], res[1], res[2], res[3]);
}

// ---------------------------------------------------------------------------
// Repack v2 (window-pair) + fused window max. pk2 replaces packbf
// (bit-identical RNE, 1 VALU vs ~8).
// ---------------------------------------------------------------------------
__global__ __launch_bounds__(512) void k_repack(
    const float* __restrict__ e0, const float* __restrict__ e1,
    const float* __restrict__ e2, unsigned int* __restrict__ kvimg,
    unsigned int* __restrict__ qimg, float* __restrict__ qwin,
    float* __restrict__ kwin)
{
  const int fl = blockIdx.x + 32 * (blockIdx.y + 4 * blockIdx.z); // 0..383
  const int nf = (fl & 7) * 48 + (fl >> 3);      // bijective: 384 = 8*48
  const int wp = nf & 31, h = (nf >> 5) & 3, b = nf >> 7;
  const float* e = (b == 0) ? e0 : ((b == 1) ? e1 : e2);
  const int w0 = wp * 2;
  const int wy = w0 >> 3, wx0 = w0 & 7;
  const int jbase0 = (wy * 16) * 128 + wx0 * 16;
  const int t = threadIdx.x;

  __shared__ float redS[32][257];
  __shared__ float part[16][32];

  float qreg[32], kreg[32];

  // ---- K + Q ----
  const int row = t >> 5, x = t & 31;
  const int win = x >> 4, key = row * 16 + (x & 15);
  {
    const int hw = jbase0 + row * 128 + x;
    const float* eK = e + (size_t)(128 + h * 32) * P + hw;
    const float* eQ = e + (size_t)(h * 32) * P + hw;
    const int half = key >> 7, kl = key & 127;
    unsigned int* kd = kvimg + (size_t)((b * 4 + h) * 64 + w0 + win) * 8192
                       + half * 4096 + kl * 16;
    unsigned int* qd = qimg + (size_t)((b * 4 + h) * 64 + w0 + win) * 4096
                       + key * 16;
    #pragma unroll
    for (int dd = 0; dd < 16; ++dd) {
      float k0 = eK[(size_t)(2 * dd) * P], k1 = eK[(size_t)(2 * dd + 1) * P];
      kreg[2 * dd] = k0; kreg[2 * dd + 1] = k1;
      kd[dd ^ ((kl & 3) << 2)] = pk2(k0, k1);
      float q0 = eQ[(size_t)(2 * dd) * P], q1 = eQ[(size_t)(2 * dd + 1) * P];
      qreg[2 * dd] = q0; qreg[2 * dd + 1] = q1;
      qd[dd] = pk2(q0 * QSCALE, q1 * QSCALE);
    }
  }
  // ---- V: thread (vwin = t&1, half, d, q4); 2 rows x 4 float4 reads ----
  {
    const int vwin = t & 1, r = t >> 1;
    const int half = r >> 7, d = (r & 127) >> 2, q4 = r & 3;
    const int R = 8 * half + 2 * q4;
    const float* eV = e + (size_t)(256 + h * 32 + d) * P + jbase0 + vwin * 16;
    float rv[2][16];
    #pragma unroll
    for (int rr = 0; rr < 2; ++rr) {
      const float4* src = (const float4*)&eV[(R + rr) * 128];
      #pragma unroll
      for (int i = 0; i < 4; ++i) {
        float4 v = src[i];
        rv[rr][4*i] = v.x; rv[rr][4*i+1] = v.y;
        rv[rr][4*i+2] = v.z; rv[rr][4*i+3] = v.w;
      }
    }
    unsigned int* vd = kvimg + (size_t)((b * 4 + h) * 64 + w0 + vwin) * 8192
                       + half * 4096 + 2048 + d * 64;
    #pragma unroll
    for (int j = 0; j < 16; ++j) {
      const int kp2 = q4 * 16 + j;
      const int rr = j >> 3, pp = (j & 7) * 2;
      vd[kp2 ^ ((d & 7) << 2)] = pk2(rv[rr][pp], rv[rr][pp + 1]);
    }
  }
  // ---- window maxes: 4 phases (q win0, q win1, k win0, k win1) ----
  #pragma unroll
  for (int ph = 0; ph < 4; ++ph) {
    const int pwv = ph & 1;
    const bool isq = ph < 2;
    __syncthreads();
    if (win == pwv) {
      #pragma unroll
      for (int ch = 0; ch < 32; ++ch)
        redS[ch][key] = isq ? qreg[ch] : kreg[ch];
    }
    __syncthreads();
    {
      const int ch = t & 31, seg = t >> 5;       // 16 segs x 16 px
      float mx = redS[ch][seg * 16];
      #pragma unroll
      for (int i = 1; i < 16; ++i) mx = fmaxf(mx, redS[ch][seg * 16 + i]);
      part[seg][ch] = mx;
    }
    __syncthreads();
    if (t < 32) {
      float mx = part[0][t];
      #pragma unroll
      for (int s = 1; s < 16; ++s) mx = fmaxf(mx, part[s][t]);
      float* dst = isq ? qwin : kwin;
      dst[(size_t)(b * 64 + w0 + pwv) * 128 + h * 32 + t] = mx;
    }
  }
}

// ---------------------------------------------------------------------------
// MFMA flash attention (frozen round-10/12 form).
// ---------------------------------------------------------------------------
__global__ __launch_bounds__(512, 4) void k_attn_mfma(
    const unsigned int* __restrict__ kvimg, const unsigned int* __restrict__ qimg,
    const int* __restrict__ ridx, float* __restrict__ attnch)
{
  const int fl = blockIdx.x + 64 * (blockIdx.y + 4 * blockIdx.z);
  const int nf = (fl & 7) * 96 + (fl >> 3);       // bijective XCD swizzle
  const int w = nf & 63, h = (nf >> 6) & 3, b = nf >> 8;
  const int tid = threadIdx.x;
  const int wv = tid >> 6, lane = tid & 63;
  const int qi = lane & 15, g = lane >> 4;
  const int wy = w >> 3, wx = w & 7;

  __shared__ __align__(16) unsigned int kvbuf[2][4096];   // 2 x 16KB

  const unsigned int* kwin = kvimg + (size_t)((b * 4 + h) * 64) * 8192;
  const unsigned int* qwin = qimg + (size_t)((b * 4 + h) * 64 + w) * 4096;

  // Q fragments: lane (qi,g), tile s: Q[q=(wv*2+s)*16+qi][d=8g..8g+7]
  bf16x8 qv[2];
  #pragma unroll
  for (int s = 0; s < 2; ++s) {
    union { uint4 u; bf16x8 v; } tq;
    tq.u = *(const uint4*)(qwin + ((wv * 2 + s) * 16 + qi) * 16 + g * 4);
    qv[s] = tq.v;
  }
  const int4 jv = *(const int4*)(ridx + (b * 64 + w) * 4);
  const int ja[4] = {jv.x, jv.y, jv.z, jv.w};

  const f32x4 fz = {0.f, 0.f, 0.f, 0.f};
  float m[2], l[2];
  f32x4 acc[2][2];
  #pragma unroll
  for (int s = 0; s < 2; ++s) {
    m[s] = -3.0e38f; l[s] = 0.f; acc[s][0] = fz; acc[s][1] = fz;
  }

  // prologue: load chunk 0 into regs
  uint4 st0, st1;
  {
    const uint4* s4 = (const uint4*)(kwin + (size_t)ja[0] * 8192);
    st0 = s4[tid]; st1 = s4[512 + tid];
  }

#define SOFTMAX_PACK(SC, S, PB) {                                           \
    float wmax = -3.0e38f;                                                  \
    _Pragma("unroll") for (int c = 0; c < 4; ++c)                           \
      _Pragma("unroll") for (int u = 0; u < 2; ++u)                         \
        _Pragma("unroll") for (int t2 = 0; t2 < 4; ++t2)                    \
          wmax = fmaxf(wmax, SC[c][u][t2]);                                 \
    wmax = fmaxf(wmax, __shfl_xor(wmax, 16, 64));                           \
    wmax = fmaxf(wmax, __shfl_xor(wmax, 32, 64));                           \
    const float mnew = fmaxf(m[S], wmax);                                   \
    const float corr = EXP2F(m[S] - mnew);                                  \
    m[S] = mnew;                                                            \
    acc[S][0] *= corr; acc[S][1] *= corr;                                   \
    float psum = 0.f;                                                       \
    _Pragma("unroll") for (int c = 0; c < 4; ++c)                           \
      _Pragma("unroll") for (int u = 0; u < 2; ++u) {                       \
        const float p0 = EXP2F(SC[c][u][0] - mnew);                         \
        const float p1 = EXP2F(SC[c][u][1] - mnew);                         \
        const float p2 = EXP2F(SC[c][u][2] - mnew);                         \
        const float p3 = EXP2F(SC[c][u][3] - mnew);                         \
        psum += (p0 + p1) + (p2 + p3);                                      \
        PB[c][2 * u]     = pk2(p0, p1);                                     \
        PB[c][2 * u + 1] = pk2(p2, p3);                                     \
      }                                                                     \
    l[S] = l[S] * corr + psum;                                              \
  }

  for (int ch = 0; ch < 8; ++ch) {
    // write chunk ch (staged in regs) into buf[ch&1]
    {
      uint4* d4 = (uint4*)kvbuf[ch & 1];
      d4[tid] = st0; d4[512 + tid] = st1;
    }
    // issue chunk ch+1 loads — latency hides under this chunk's compute
    if (ch < 7) {
      const int nx = ch + 1;
      const uint4* s4 = (const uint4*)(kwin + (size_t)ja[nx >> 1] * 8192
                                       + (size_t)(nx & 1) * 4096);
      st0 = s4[tid]; st1 = s4[512 + tid];
    }
    __syncthreads();   // chunk ch visible; prior chunk's readers are done

    const unsigned int* bc = kvbuf[ch & 1];
    const bf16x8* kp = (const bf16x8*)bc;
    const unsigned short* vsh = (const unsigned short*)(bc + 2048);

    f32x4 scA[4][2], scB[4][2];
    __builtin_amdgcn_s_setprio(1);
    #pragma unroll
    for (int c = 0; c < 4; ++c) {
      #pragma unroll
      for (int u = 0; u < 2; ++u) {
        const int key = 32 * c + 8 * (qi >> 2) + 4 * u + (qi & 3);
        const bf16x8 ka = kp[key * 4 + (g ^ (qi & 3))];
        scA[c][u] = __builtin_amdgcn_mfma_f32_16x16x32_bf16(ka, qv[0], fz, 0, 0, 0);
        scB[c][u] = __builtin_amdgcn_mfma_f32_16x16x32_bf16(ka, qv[1], fz, 0, 0, 0);
      }
    }
    __builtin_amdgcn_s_setprio(0);
    unsigned int pbA[4][4], pbB[4][4];
    SOFTMAX_PACK(scA, 0, pbA);
    SOFTMAX_PACK(scB, 1, pbB);
    __builtin_amdgcn_s_setprio(1);
    #pragma unroll
    for (int c = 0; c < 4; ++c) {
      #pragma unroll
      for (int dt = 0; dt < 2; ++dt) {
        const int d0 = dt * 16 + qi;
        const bf16x8 va = *(const bf16x8*)&vsh[
            (unsigned)((d0 * 128 + 32 * c + 8 * g) ^ ((d0 & 7) << 3))];
        union { unsigned int u4[4]; bf16x8 v; } pva, pvb;
        pva.u4[0] = pbA[c][0]; pva.u4[1] = pbA[c][1];
        pva.u4[2] = pbA[c][2]; pva.u4[3] = pbA[c][3];
        pvb.u4[0] = pbB[c][0]; pvb.u4[1] = pbB[c][1];
        pvb.u4[2] = pbB[c][2]; pvb.u4[3] = pbB[c][3];
        acc[0][dt] = __builtin_amdgcn_mfma_f32_16x16x32_bf16(va, pva.v, acc[0][dt], 0, 0, 0);
        acc[1][dt] = __builtin_amdgcn_mfma_f32_16x16x32_bf16(va, pvb.v, acc[1][dt], 0, 0, 0);
      }
    }
    __builtin_amdgcn_s_setprio(0);
  }
#undef SOFTMAX_PACK

  // epilogue: lane (qi,g) holds O^T[d = dt*16+4g+t][q = (wv*2+s)*16+qi]
  #pragma unroll
  for (int s = 0; s < 2; ++s) {
    float lsum = l[s];
    lsum += __shfl_xor(lsum, 16, 64);
    lsum += __shfl_xor(lsum, 32, 64);
    const float inv = 1.f / lsum;
    const int hwq = (wy * 16 + wv * 2 + s) * 128 + wx * 16 + qi;
    #pragma unroll
    for (int dt = 0; dt < 2; ++dt)
      #pragma unroll
      for (int t = 0; t < 4; ++t) {
        const int d = dt * 16 + 4 * g + t;
        attnch[(size_t)(b * 128 + h * 32 + d) * P + hwq] = acc[s][dt][t] * inv;
      }
  }
}

// ---------------------------------------------------------------------------
extern "C" void kernel_launch(void* const* d_in, const int* in_sizes, int n_in,
                              void* d_out, int out_size, void* d_ws, size_t ws_size,
                              hipStream_t stream)
{
  (void)in_sizes; (void)n_in; (void)out_size;
  const float* x      = (const float*)d_in[0];
  const float* qkv2_w = (const float*)d_in[1];
  const float* dw3_w  = (const float*)d_in[2];
  const float* pw3_w  = (const float*)d_in[3];
  const float* dw5_w  = (const float*)d_in[4];
  const float* pw5_w  = (const float*)d_in[5];
  const float* mlp_w  = (const float*)d_in[6];
  const float* mlp_b  = (const float*)d_in[7];
  const float* proj_w = (const float*)d_in[8];
  const float* ln_g   = (const float*)d_in[9];
  const float* ln_b   = (const float*)d_in[10];

  float* ws = (float*)d_ws;
  const size_t CH = (size_t)384 * P;
  float* qkv    = ws;
  float* dwt3   = ws + CH;
  float* y3     = ws + 2 * CH;
  float* y5     = ws + 3 * CH;           // also dwt5 (in-place pw5)
  float* qwin   = ws + 5 * CH;
  float* kwin   = qwin + 3 * 64 * 128;
  int*   ridx   = (int*)(kwin + 3 * 64 * 128);
  float* Wc     = (float*)(ridx + 768);
  float* bc     = Wc + 128 * 384;
  unsigned int* kvimg = (unsigned int*)(ws + 4 * CH);
  unsigned int* qimg  = (unsigned int*)dwt3;
  float* attnch = y3;
  (void)ws_size;

  // fold mlp into proj (independent of main chain)
  k_fold<<<dim3(128, 3), 128, 0, stream>>>(proj_w, mlp_w, mlp_b, Wc, bc);

  // qkv: 64oc x 128px tiles -> 768 blocks (3/CU even)
  k_conv_mfma<2, 2><<<dim3(128, 6, 1), 256, 0, stream>>>(x, qkv2_w, nullptr, qkv, 128, 0, 0);
  // fused depthwise 3x3 + 5x5
  k_dwf<<<dim3(384, 8), 256, 0, stream>>>(qkv, dw3_w, dw5_w, dwt3, y5);
  // both grouped-pointwise branches in one launch
  k_pw2<<<dim3(64, 12, 2), 256, 0, stream>>>(dwt3, pw3_w, y3, y5, pw5_w, y5);
  // repack (window-pair) + fused window max
  k_repack<<<dim3(32, 4, 3), 512, 0, stream>>>(qkv, y3, y5, kvimg, qimg, qwin, kwin);
  k_topk<<<dim3(16, 3), 256, 0, stream>>>(qwin, kwin, ridx);
  k_attn_mfma<<<dim3(64, 4, 3), 512, 0, stream>>>(kvimg, qimg, ridx, attnch);
  // fused mlp+proj+LayerNorm: writes d_out directly
  k_projln<<<dim3(256), 256, 0, stream>>>(attnch, Wc, bc, ln_g, ln_b, (float*)d_out);
}